// Round 5
// baseline (154.770 us; speedup 1.0000x reference)
//
#include <hip/hip_runtime.h>
#include <math.h>

typedef __attribute__((ext_vector_type(8))) short bf16x8;
typedef __attribute__((ext_vector_type(4))) float f32x4;

#define RFEAT 256
#define ZN 20480                        // 256 feats x 80 cols (64 v + ksum + 15 pad)
#define NBKV 256                        // kv blocks; 4 chunks of 64 rows each

// exp2-domain: phi = ratio * exp(x.P'*sc - sc^2*||x||^2/2) = 2^( mfma(x, sc*log2e*P) + rc )
// rc = -0.5*sc^2*log2e*||x||^2 + log2(ratio);  sc = 64^-0.25 = 2^-1.5, ratio = 1/16
#define SCLOG2E 0.51006971688f          // sc * log2(e)
#define RC_COEF -0.09016844006f         // -0.5 * sc^2 * log2(e)
#define LOG2RATIO -4.0f                 // log2(1/16)

__device__ __forceinline__ unsigned short f2bf(float f) {
    union { float f; unsigned int u; } v; v.f = f;
    unsigned int r = v.u + 0x7FFFu + ((v.u >> 16) & 1u);   // RNE
    return (unsigned short)(r >> 16);
}

// ---------------- prep: Vb frags + Pb frags + zero Zf ----------------
// Vb frag F = s*4+nt, lane l, elem j: B[k][n] = V[s*32 + (l>>4)*8 + j][nt*16 + (l&15)].
// Pb frag f = kstep*16+nt: B[k][n] = SCLOG2E*P[n][k], n = nt*16+(l&15), k = kstep*32+(l>>4)*8+j.
__global__ __launch_bounds__(256)
void prep_kernel(const float* __restrict__ P, const float* __restrict__ V,
                 unsigned short* __restrict__ Pb, unsigned short* __restrict__ Vb,
                 float* __restrict__ Zf)
{
    const int t = threadIdx.x, l = t & 63;
    if (blockIdx.x < 2048) {            // Vb: 2048 blocks x 4 waves = 8192 frags
        const int F = blockIdx.x * 4 + (t >> 6);
        const float* src = V + (size_t)((F >> 2) * 32 + (l >> 4) * 8) * 64 + (F & 3) * 16 + (l & 15);
        bf16x8 fr;
        #pragma unroll
        for (int j = 0; j < 8; j++) fr[j] = (short)f2bf(src[j * 64]);
        *(bf16x8*)(Vb + (size_t)F * 512 + l * 8) = fr;
        return;
    }
    if (blockIdx.x == 2048) {           // Pb (one block, 4 waves x 8 frags)
        const int g = t >> 6;
        for (int f = g * 8; f < g * 8 + 8; f++) {
            const int kstep = f >> 4, nt = f & 15;
            const float* src = P + (nt * 16 + (l & 15)) * 64 + kstep * 32 + (l >> 4) * 8;
            bf16x8 frag;
            #pragma unroll
            for (int j = 0; j < 8; j++) frag[j] = (short)f2bf(SCLOG2E * src[j]);
            *(bf16x8*)(Pb + f * 512 + l * 8) = frag;
        }
        return;
    }
    // zero Zf: blocks 2049..2128
    const int idx = (blockIdx.x - 2049) * 256 + t;
    Zf[idx] = 0.f;
}

// ---------------- phi of a 64-row chunk -> LDS (bf16), via MFMA ----------------
// TRANS=true : phi_lds[col*LDP + row]  (packed u32 writes; for kv stage)
// TRANS=false: phi_lds[row*LDP + col]  (for q stage)
template<int LDP, bool TRANS>
__device__ __forceinline__ void phi_chunk(const float* __restrict__ X, int chunkBase,
                                          const unsigned short* __restrict__ Pb,
                                          unsigned short* phi_lds, float* rc)
{
    const int t = threadIdx.x, l = t & 63, w = t >> 6;
    if (t < 64) {   // per-row constant (exp2 domain)
        const float4* xr = (const float4*)(X + (size_t)(chunkBase + t) * 64);
        float s0 = 0.f, s1 = 0.f;
        #pragma unroll
        for (int j = 0; j < 16; j += 2) {
            float4 a = xr[j];     s0 += a.x*a.x + a.y*a.y + a.z*a.z + a.w*a.w;
            float4 b = xr[j + 1]; s1 += b.x*b.x + b.y*b.y + b.z*b.z + b.w*b.w;
        }
        rc[t] = RC_COEF * (s0 + s1) + LOG2RATIO;
    }
    // A-frags: wave w owns rows [chunkBase+16w, +16); m = l&15, k = (l>>4)*8 + j (+32 for kstep 1)
    const float* ar = X + (size_t)(chunkBase + 16 * w + (l & 15)) * 64 + (l >> 4) * 8;
    bf16x8 a0, a1;
    #pragma unroll
    for (int j = 0; j < 8; j++) a0[j] = (short)f2bf(ar[j]);
    #pragma unroll
    for (int j = 0; j < 8; j++) a1[j] = (short)f2bf(ar[32 + j]);
    __syncthreads();   // rc ready; also: all threads finished reading previous chunk's phi_lds
    const float4 rcv = *(const float4*)(rc + 16 * w + 4 * (l >> 4));   // rc rows for D regs 0..3
    #pragma unroll
    for (int nt = 0; nt < 16; nt++) {
        bf16x8 b0 = *(const bf16x8*)(Pb + nt * 512 + l * 8);
        bf16x8 b1 = *(const bf16x8*)(Pb + (16 + nt) * 512 + l * 8);
        f32x4 acc = (f32x4){rcv.x, rcv.y, rcv.z, rcv.w};   // C-in = rc (free add)
        acc = __builtin_amdgcn_mfma_f32_16x16x32_bf16(a0, b0, acc, 0, 0, 0);
        acc = __builtin_amdgcn_mfma_f32_16x16x32_bf16(a1, b1, acc, 0, 0, 0);
        float p0 = __builtin_amdgcn_exp2f(acc[0]);
        float p1 = __builtin_amdgcn_exp2f(acc[1]);
        float p2 = __builtin_amdgcn_exp2f(acc[2]);
        float p3 = __builtin_amdgcn_exp2f(acc[3]);
        const int col = nt * 16 + (l & 15);
        unsigned int w0 = (unsigned int)f2bf(p0) | ((unsigned int)f2bf(p1) << 16);
        unsigned int w1 = (unsigned int)f2bf(p2) | ((unsigned int)f2bf(p3) << 16);
        if (TRANS) {   // rows (l>>4)*4 + 0..3 contiguous -> 2 packed u32 writes
            unsigned int* dst = (unsigned int*)(phi_lds + col * LDP + 16 * w + 4 * (l >> 4));
            dst[0] = w0;
            dst[1] = w1;
        } else {
            const int rb = (16 * w + (l >> 4) * 4) * LDP + col;
            phi_lds[rb]           = (unsigned short)(w0);
            phi_lds[rb + LDP]     = (unsigned short)(w0 >> 16);
            phi_lds[rb + 2 * LDP] = (unsigned short)(w1);
            phi_lds[rb + 3 * LDP] = (unsigned short)(w1 >> 16);
        }
    }
    __syncthreads();
}

// ---------------- kv_atomic: Zf += phi(K)^T @ [V | 1] over this block's rows ----------------
__global__ __launch_bounds__(256, 2)
void kv_atomic_kernel(const float* __restrict__ Kp, const unsigned short* __restrict__ Vb,
                      const unsigned short* __restrict__ Pb, float* __restrict__ Zf)
{
    __shared__ __align__(16) unsigned short phi_lds[RFEAT * 72];   // [feat][krow], padded
    __shared__ __align__(16) float rc[64];
    const int t = threadIdx.x, l = t & 63, w = t >> 6;

    f32x4 acc[4][5];
    #pragma unroll
    for (int mt = 0; mt < 4; mt++)
        #pragma unroll
        for (int nt = 0; nt < 5; nt++) acc[mt][nt] = (f32x4){0.f, 0.f, 0.f, 0.f};

    bf16x8 ones;   // B-frag for ksum column: B[k][64]=1, rest 0 -> lanes with (l&15)==0
    #pragma unroll
    for (int j = 0; j < 8; j++) ones[j] = (short)(((l & 15) == 0) ? 0x3F80 : 0);

    const int base = blockIdx.x * 256;            // 4 chunks of 64 rows
    for (int c = 0; c < 4; c++) {
        const int cb = base + c * 64;
        phi_chunk<72, true>(Kp, cb, Pb, phi_lds, rc);
        #pragma unroll
        for (int ks = 0; ks < 2; ks++) {
            bf16x8 af[4];   // A = phi(K)^T: m=feature, k=krow; wave w owns feats [64w,+64)
            #pragma unroll
            for (int mt = 0; mt < 4; mt++)
                af[mt] = *(const bf16x8*)(phi_lds + (64 * w + mt * 16 + (l & 15)) * 72
                                          + ks * 32 + (l >> 4) * 8);
            const unsigned short* vb = Vb + ((size_t)((cb >> 5) + ks) * 4) * 512 + l * 8;
            bf16x8 bf4[4];
            #pragma unroll
            for (int nt = 0; nt < 4; nt++) bf4[nt] = *(const bf16x8*)(vb + nt * 512);
            #pragma unroll
            for (int mt = 0; mt < 4; mt++) {
                #pragma unroll
                for (int nt = 0; nt < 4; nt++)
                    acc[mt][nt] = __builtin_amdgcn_mfma_f32_16x16x32_bf16(af[mt], bf4[nt], acc[mt][nt], 0, 0, 0);
                acc[mt][4] = __builtin_amdgcn_mfma_f32_16x16x32_bf16(af[mt], ones, acc[mt][4], 0, 0, 0);
            }
        }
    }
    // accumulate into Zf via HW f32 atomics; skip always-zero pad cols (nt==4, (l&15)!=0)
    #pragma unroll
    for (int mt = 0; mt < 4; mt++) {
        #pragma unroll
        for (int nt = 0; nt < 5; nt++) {
            if (nt == 4 && (l & 15) != 0) continue;
            #pragma unroll
            for (int reg = 0; reg < 4; reg++)
                unsafeAtomicAdd(&Zf[(64 * w + mt * 16 + (l >> 4) * 4 + reg) * 80
                                    + nt * 16 + (l & 15)], acc[mt][nt][reg]);
        }
    }
}

// ---------------- q_out: out = normalize( phi(Q) @ Z ) ----------------
__global__ __launch_bounds__(256, 2)
void q_out_kernel(const float* __restrict__ Q, const unsigned short* __restrict__ Pb,
                  const float* __restrict__ Zf, float* __restrict__ out)
{
    __shared__ __align__(16) unsigned short phi_lds[64 * 272];   // [row][feat], padded
    __shared__ __align__(16) unsigned short zb_lds[ZN];          // Z bf16, B-frag octet layout
    __shared__ __align__(16) float rc[64];
    const int t = threadIdx.x, l = t & 63, w = t >> 6;
    const int base = blockIdx.x * 64;

    // Zf (f32, global) -> zb_lds (bf16 frags): element (m,n) at ((m>>3)*80 + n)*8 + (m&7)
    #pragma unroll 4
    for (int i = 0; i < 80; i++) {
        const int idx = i * 256 + t;
        const int m = idx / 80, n = idx - m * 80;
        zb_lds[((m >> 3) * 80 + n) * 8 + (m & 7)] = f2bf(Zf[idx]);
    }
    // phi_chunk's internal __syncthreads() fences zb_lds before use
    phi_chunk<272, false>(Q, base, Pb, phi_lds, rc);

    f32x4 acc[5];
    #pragma unroll
    for (int nt = 0; nt < 5; nt++) acc[nt] = (f32x4){0.f, 0.f, 0.f, 0.f};

    #pragma unroll
    for (int ks = 0; ks < 8; ks++) {
        bf16x8 a = *(const bf16x8*)(phi_lds + (16 * w + (l & 15)) * 272 + ks * 32 + (l >> 4) * 8);
        #pragma unroll
        for (int nt = 0; nt < 5; nt++) {
            bf16x8 b = *(const bf16x8*)(zb_lds + ((ks * 4 + (l >> 4)) * 80 + nt * 16 + (l & 15)) * 8);
            acc[nt] = __builtin_amdgcn_mfma_f32_16x16x32_bf16(a, b, acc[nt], 0, 0, 0);
        }
    }
    // denom = output column 64 -> tile 4, lanes with (l&15)==0; broadcast within 16-group
    float inv[4];
    #pragma unroll
    for (int reg = 0; reg < 4; reg++) {
        float den = __shfl(acc[4][reg], (l & 48));
        inv[reg] = 1.0f / den;
    }
    const int row = base + 16 * w + (l >> 4) * 4;
    #pragma unroll
    for (int nt = 0; nt < 4; nt++)
        #pragma unroll
        for (int reg = 0; reg < 4; reg++)
            out[(size_t)(row + reg) * 64 + nt * 16 + (l & 15)] = acc[nt][reg] * inv[reg];
}

extern "C" void kernel_launch(void* const* d_in, const int* in_sizes, int n_in,
                              void* d_out, int out_size, void* d_ws, size_t ws_size,
                              hipStream_t stream) {
    const float* q = (const float*)d_in[0];
    const float* k = (const float*)d_in[1];
    const float* v = (const float*)d_in[2];
    const float* P = (const float*)d_in[3];
    float* out = (float*)d_out;

    unsigned short* Pb = (unsigned short*)d_ws;                  // 32 frags * 1KB = 32KB
    float* Zf = (float*)((char*)d_ws + 32768);                   // 20480 f32 = 80KB
    unsigned short* Vb = (unsigned short*)((char*)d_ws + 32768 + 81920);  // 8192 frags = 8MB

    prep_kernel<<<2129, 256, 0, stream>>>(P, v, Pb, Vb, Zf);
    kv_atomic_kernel<<<NBKV, 256, 0, stream>>>(k, Vb, Pb, Zf);
    q_out_kernel<<<1024, 256, 0, stream>>>(q, Pb, Zf, out);
}